// Round 1
// baseline (139.445 us; speedup 1.0000x reference)
//
#include <hip/hip_runtime.h>
#include <math.h>

// Problem constants (B,C,H,W) = (64,512,28,28)
#define NB    64
#define NC    512
#define CST   784          // H*W = channel stride (elements)
#define NCOL  50176        // B*H*W columns
#define SEG   64           // channels per segment
#define NSEG  8            // 512/64
#define GSZ   25690112     // B*C*H*W

// ws layout: bytes [0,16): double loss accumulator (+pad)
//            then SA[NSEG][NCOL] floats, then SB[NSEG][NCOL] floats (~3.2 MB)

__global__ __launch_bounds__(256) void k_partial(const float* __restrict__ x,
                                                 const float* __restrict__ w,
                                                 float* __restrict__ SA,
                                                 float* __restrict__ SB) {
    const int p = blockIdx.x * 256 + threadIdx.x;   // column id (grid exact)
    const int s = blockIdx.y;                        // segment id
    const int b = p / CST;
    const int hw = p - b * CST;
    const float* xp = x + (size_t)b * (NC * CST) + hw;
    const int k0 = s * SEG;

    float xv = xp[(size_t)k0 * CST];
    float sA = 0.f, sB = 0.f;
    #pragma unroll 8
    for (int j = 0; j < SEG; ++j) {
        const int k = k0 + j;
        float xn = 0.f;
        if (k < NC - 1) {
            xn = xp[(size_t)(k + 1) * CST];
            const float wk = w[k];
            sA = fmaf(xv, wk, sA);   // a[k]  = x[k]  * w[k]
            sB = fmaf(xn, wk, sB);   // b2[k] = x[k+1]* w[k]
        }
        xv = xn;
    }
    SA[s * NCOL + p] = sA;
    SB[s * NCOL + p] = sB;
}

__global__ __launch_bounds__(256) void k_emit(const float* __restrict__ x,
                                              const float* __restrict__ w,
                                              const float* __restrict__ SA,
                                              const float* __restrict__ SB,
                                              float* __restrict__ g,
                                              double* __restrict__ acc) {
    const int p = blockIdx.x * 256 + threadIdx.x;
    const int s = blockIdx.y;
    const int b = p / CST;
    const int hw = p - b * CST;
    const size_t base = (size_t)b * (NC * CST) + hw;
    const float* xp = x + base;
    float* gp = g + base;

    // cross-segment offsets for this column
    float offA = 0.f, offB = 0.f, sbs = 0.f;
    #pragma unroll
    for (int t = 0; t < NSEG; ++t) {
        const float sa = SA[t * NCOL + p];
        const float sb = SB[t * NCOL + p];
        if (t < s)  offA += sa;
        if (t > s)  offB += sb;
        if (t == s) sbs = sb;
    }

    const int k0 = s * SEG;
    // g[k0] = prefA(k0) + sufB(k0) = offA + (SB[s] + offB)
    float r = offA + offB + sbs;
    float xv = xp[(size_t)k0 * CST];
    float lsum = 0.f;
    #pragma unroll 8
    for (int j = 0; j < SEG; ++j) {
        const int k = k0 + j;
        const float xn = (k < NC - 1) ? xp[(size_t)(k + 1) * CST] : 0.f;
        gp[(size_t)k * CST] = r;
        const float d = r - xv;
        lsum = fmaf(d, d, lsum);
        if (k < NC - 1) r = fmaf(w[k], (xv - xn), r);  // g[k+1] = g[k] + w[k]*(x[k]-x[k+1])
        xv = xn;
    }

    // wave reduction (64 lanes) then one double atomic per wave
    #pragma unroll
    for (int off = 32; off > 0; off >>= 1)
        lsum += __shfl_down(lsum, off, 64);
    if ((threadIdx.x & 63) == 0)
        atomicAdd(acc, (double)lsum);
}

__global__ void k_final(const double* __restrict__ acc, float* __restrict__ out) {
    out[0] = (float)(sqrt(*acc) * 0.0025);
}

extern "C" void kernel_launch(void* const* d_in, const int* in_sizes, int n_in,
                              void* d_out, int out_size, void* d_ws, size_t ws_size,
                              hipStream_t stream) {
    const float* x = (const float*)d_in[0];
    const float* w = (const float*)d_in[1];
    float* g = (float*)d_out;
    double* acc = (double*)d_ws;
    float* SA = (float*)((char*)d_ws + 16);
    float* SB = SA + NSEG * NCOL;

    hipMemsetAsync(d_ws, 0, 16, stream);   // zero loss accumulator every launch

    dim3 grid(NCOL / 256, NSEG);
    k_partial<<<grid, dim3(256), 0, stream>>>(x, w, SA, SB);
    k_emit<<<grid, dim3(256), 0, stream>>>(x, w, SA, SB, g, acc);
    k_final<<<1, 1, 0, stream>>>(acc, g + GSZ);
}

// Round 2
// 61.002 us; speedup vs baseline: 2.2859x; 2.2859x over previous
//
#include <hip/hip_runtime.h>
#include <math.h>

// (B,C,H,W) = (64,512,28,28)
#define NC    512
#define CST   784          // H*W
#define NCOL  50176        // B*H*W
#define NG    12544        // NCOL/4 column-groups (float4 along hw)
#define GPB   196          // groups per image plane = CST/4
#define SEG   64
#define NSEG  8
#define GSZ   25690112
#define TPB   64
#define NBX   196          // NG/TPB
#define NPART (NBX*NSEG)   // 1568 per-block loss partials

// ws layout: [0,8192): float part[1568]; then SA[NSEG][NG] float4, SB same (~3.2MB)

__global__ __launch_bounds__(TPB) void k_partial(const float* __restrict__ x,
                                                 const float* __restrict__ w,
                                                 float4* __restrict__ SA,
                                                 float4* __restrict__ SB) {
    const int p4 = blockIdx.x * TPB + threadIdx.x;
    const int s  = blockIdx.y;
    const int b  = p4 / GPB;
    const int hw = (p4 - b * GPB) * 4;
    const float* xp = x + (size_t)b * (NC * CST) + hw;
    const int k0 = s * SEG;
    const int jend = (s == NSEG - 1) ? SEG - 1 : SEG;   // block-uniform

    float4 xv = *(const float4*)(xp + (size_t)k0 * CST);
    float sAx=0,sAy=0,sAz=0,sAw=0, sBx=0,sBy=0,sBz=0,sBw=0;
    #pragma unroll 8
    for (int j = 0; j < jend; ++j) {
        const int k = k0 + j;
        const float4 xn = *(const float4*)(xp + (size_t)(k + 1) * CST);
        const float wk = w[k];
        sAx = fmaf(xv.x, wk, sAx);  sAy = fmaf(xv.y, wk, sAy);
        sAz = fmaf(xv.z, wk, sAz);  sAw = fmaf(xv.w, wk, sAw);
        sBx = fmaf(xn.x, wk, sBx);  sBy = fmaf(xn.y, wk, sBy);
        sBz = fmaf(xn.z, wk, sBz);  sBw = fmaf(xn.w, wk, sBw);
        xv = xn;
    }
    SA[s * NG + p4] = make_float4(sAx, sAy, sAz, sAw);
    SB[s * NG + p4] = make_float4(sBx, sBy, sBz, sBw);
}

__global__ __launch_bounds__(TPB) void k_emit(const float* __restrict__ x,
                                              const float* __restrict__ w,
                                              const float4* __restrict__ SA,
                                              const float4* __restrict__ SB,
                                              float* __restrict__ g,
                                              float* __restrict__ part) {
    const int p4 = blockIdx.x * TPB + threadIdx.x;
    const int s  = blockIdx.y;
    const int b  = p4 / GPB;
    const int hw = (p4 - b * GPB) * 4;
    const size_t base = (size_t)b * (NC * CST) + hw;
    const float* xp = x + base;
    float* gp = g + base;

    // g[k0] = sum_{t<s} SA[t] + sum_{t>=s} SB[t]   (per column)
    float rx=0, ry=0, rz=0, rw=0;
    for (int t = 0; t < s; ++t) {
        const float4 v = SA[t * NG + p4];
        rx += v.x; ry += v.y; rz += v.z; rw += v.w;
    }
    for (int t = s; t < NSEG; ++t) {
        const float4 v = SB[t * NG + p4];
        rx += v.x; ry += v.y; rz += v.z; rw += v.w;
    }

    const int k0 = s * SEG;
    const int jend = (s == NSEG - 1) ? SEG - 1 : SEG;   // block-uniform
    float4 xv = *(const float4*)(xp + (size_t)k0 * CST);
    float lx=0, ly=0, lz=0, lw=0;
    #pragma unroll 8
    for (int j = 0; j < jend; ++j) {
        const int k = k0 + j;
        const float4 xn = *(const float4*)(xp + (size_t)(k + 1) * CST);
        *(float4*)(gp + (size_t)k * CST) = make_float4(rx, ry, rz, rw);
        const float dx = rx - xv.x, dy = ry - xv.y, dz = rz - xv.z, dw = rw - xv.w;
        lx = fmaf(dx, dx, lx); ly = fmaf(dy, dy, ly);
        lz = fmaf(dz, dz, lz); lw = fmaf(dw, dw, lw);
        const float wk = w[k];
        rx = fmaf(wk, xv.x - xn.x, rx);  ry = fmaf(wk, xv.y - xn.y, ry);
        rz = fmaf(wk, xv.z - xn.z, rz);  rw = fmaf(wk, xv.w - xn.w, rw);
        xv = xn;
    }
    if (s == NSEG - 1) {   // channel 511 epilogue: store + loss, no recurrence
        *(float4*)(gp + (size_t)(NC - 1) * CST) = make_float4(rx, ry, rz, rw);
        const float dx = rx - xv.x, dy = ry - xv.y, dz = rz - xv.z, dw = rw - xv.w;
        lx = fmaf(dx, dx, lx); ly = fmaf(dy, dy, ly);
        lz = fmaf(dz, dz, lz); lw = fmaf(dw, dw, lw);
    }

    float ls = (lx + ly) + (lz + lw);
    #pragma unroll
    for (int off = 32; off; off >>= 1) ls += __shfl_down(ls, off, 64);
    if (threadIdx.x == 0) part[blockIdx.y * NBX + blockIdx.x] = ls;
}

__global__ __launch_bounds__(256) void k_final(const float* __restrict__ part,
                                               float* __restrict__ out) {
    double s = 0.0;
    for (int i = threadIdx.x; i < NPART; i += 256) s += (double)part[i];
    #pragma unroll
    for (int off = 32; off; off >>= 1) s += __shfl_down(s, off, 64);
    __shared__ double sm[4];
    if ((threadIdx.x & 63) == 0) sm[threadIdx.x >> 6] = s;
    __syncthreads();
    if (threadIdx.x == 0) {
        const double t = sm[0] + sm[1] + sm[2] + sm[3];
        out[0] = (float)(sqrt(t) * 0.0025);
    }
}

extern "C" void kernel_launch(void* const* d_in, const int* in_sizes, int n_in,
                              void* d_out, int out_size, void* d_ws, size_t ws_size,
                              hipStream_t stream) {
    const float* x = (const float*)d_in[0];
    const float* w = (const float*)d_in[1];
    float* g = (float*)d_out;
    float* part = (float*)d_ws;
    float4* SA = (float4*)((char*)d_ws + 8192);
    float4* SB = SA + NSEG * NG;

    dim3 grid(NBX, NSEG);
    k_partial<<<grid, dim3(TPB), 0, stream>>>(x, w, SA, SB);
    k_emit<<<grid, dim3(TPB), 0, stream>>>(x, w, SA, SB, g, part);
    k_final<<<1, 256, 0, stream>>>(part, g + GSZ);
}

// Round 3
// 57.404 us; speedup vs baseline: 2.4292x; 1.0627x over previous
//
#include <hip/hip_runtime.h>
#include <math.h>

// (B,C,H,W) = (64,512,28,28)
#define NC    512
#define CST   784          // H*W
#define GPB2  392          // float2 groups per image plane (CST/2)
#define SEG   64
#define NSEG  8
#define GSZ   25690112
#define NBLK  392          // 25088 float2-groups / 64 lanes

__global__ __launch_bounds__(512) void k_fused(const float* __restrict__ x,
                                               const float* __restrict__ w,
                                               float* __restrict__ g,
                                               float* __restrict__ part) {
    const int lane = threadIdx.x & 63;
    const int s    = threadIdx.x >> 6;          // wave id = channel segment
    const int p2   = blockIdx.x * 64 + lane;    // float2 column-group id
    const int b    = p2 / GPB2;
    const int hw   = (p2 - b * GPB2) * 2;
    const size_t base = (size_t)b * (NC * CST) + hw;
    const float* xp = x + base;
    float*       gp = g + base;
    const int k0   = s * SEG;
    const int jend = (s == NSEG - 1) ? SEG - 1 : SEG;   // wave-uniform

    __shared__ float2 sA[NSEG][64];
    __shared__ float2 sB[NSEG][64];
    __shared__ float  lpart[NSEG];

    // ---- phase A: per-segment partial sums ----
    float2 xv = *(const float2*)(xp + (size_t)k0 * CST);
    float ax = 0, ay = 0, bx = 0, by = 0;
    #pragma unroll 8
    for (int j = 0; j < jend; ++j) {
        const int k = k0 + j;
        const float2 xn = *(const float2*)(xp + (size_t)(k + 1) * CST);
        const float wk = w[k];
        ax = fmaf(xv.x, wk, ax);  ay = fmaf(xv.y, wk, ay);   // A[k] = x[k]  *w[k]
        bx = fmaf(xn.x, wk, bx);  by = fmaf(xn.y, wk, by);   // B[k] = x[k+1]*w[k]
        xv = xn;
    }
    sA[s][lane] = make_float2(ax, ay);
    sB[s][lane] = make_float2(bx, by);
    __syncthreads();

    // ---- starting value: g[k0] = sum_{t<s} A_t + sum_{t>=s} B_t ----
    float rx = 0, ry = 0;
    #pragma unroll
    for (int t = 0; t < NSEG; ++t) {
        const float2 va = sA[t][lane];
        const float2 vb = sB[t][lane];
        if (t < s) { rx += va.x; ry += va.y; }
        else       { rx += vb.x; ry += vb.y; }
    }

    // ---- phase B: emit g + loss (x re-read is L2/L3-hot) ----
    xv = *(const float2*)(xp + (size_t)k0 * CST);
    float lx = 0, ly = 0;
    #pragma unroll 8
    for (int j = 0; j < jend; ++j) {
        const int k = k0 + j;
        const float2 xn = *(const float2*)(xp + (size_t)(k + 1) * CST);
        *(float2*)(gp + (size_t)k * CST) = make_float2(rx, ry);
        const float dx = rx - xv.x, dy = ry - xv.y;
        lx = fmaf(dx, dx, lx);  ly = fmaf(dy, dy, ly);
        const float wk = w[k];
        rx = fmaf(wk, xv.x - xn.x, rx);  ry = fmaf(wk, xv.y - xn.y, ry);
        xv = xn;
    }
    if (s == NSEG - 1) {   // channel 511 epilogue
        *(float2*)(gp + (size_t)(NC - 1) * CST) = make_float2(rx, ry);
        const float dx = rx - xv.x, dy = ry - xv.y;
        lx = fmaf(dx, dx, lx);  ly = fmaf(dy, dy, ly);
    }

    // ---- loss: wave reduce -> block reduce -> one float per block ----
    float ls = lx + ly;
    #pragma unroll
    for (int off = 32; off; off >>= 1) ls += __shfl_down(ls, off, 64);
    if (lane == 0) lpart[s] = ls;
    __syncthreads();
    if (threadIdx.x == 0) {
        float t = 0;
        #pragma unroll
        for (int i = 0; i < NSEG; ++i) t += lpart[i];
        part[blockIdx.x] = t;
    }
}

__global__ __launch_bounds__(256) void k_final(const float* __restrict__ part,
                                               float* __restrict__ out) {
    double s = 0.0;
    for (int i = threadIdx.x; i < NBLK; i += 256) s += (double)part[i];
    #pragma unroll
    for (int off = 32; off; off >>= 1) s += __shfl_down(s, off, 64);
    __shared__ double sm[4];
    if ((threadIdx.x & 63) == 0) sm[threadIdx.x >> 6] = s;
    __syncthreads();
    if (threadIdx.x == 0)
        out[0] = (float)(sqrt(sm[0] + sm[1] + sm[2] + sm[3]) * 0.0025);
}

extern "C" void kernel_launch(void* const* d_in, const int* in_sizes, int n_in,
                              void* d_out, int out_size, void* d_ws, size_t ws_size,
                              hipStream_t stream) {
    const float* x = (const float*)d_in[0];
    const float* w = (const float*)d_in[1];
    float* g = (float*)d_out;
    float* part = (float*)d_ws;

    k_fused<<<dim3(NBLK), dim3(512), 0, stream>>>(x, w, g, part);
    k_final<<<1, 256, 0, stream>>>(part, g + GSZ);
}

// Round 4
// 43.383 us; speedup vs baseline: 3.2143x; 1.3232x over previous
//
#include <hip/hip_runtime.h>
#include <math.h>

// (B,C,H,W) = (64,512,28,28)
#define NC    512
#define CST   784          // H*W
#define SEG   64
#define NSEG  8
#define GSZ   25690112
#define NBLK  784          // 50176 columns / 64 lanes

__global__ __launch_bounds__(512, 4) void k_fused(const float* __restrict__ x,
                                                  const float* __restrict__ w,
                                                  float* __restrict__ g,
                                                  float* __restrict__ part) {
    const int lane = threadIdx.x & 63;
    const int s    = threadIdx.x >> 6;          // wave id = channel segment
    const int p    = blockIdx.x * 64 + lane;    // column id
    const int b    = p / CST;
    const int hw   = p - b * CST;
    const size_t base = (size_t)b * (NC * CST) + hw;
    const float* xp = x + base;
    float*       gp = g + base;
    const int k0 = s * SEG;

    __shared__ float wl[NC];        // w padded: wl[511] = 0
    __shared__ float sA[NSEG][64];
    __shared__ float sB[NSEG][64];
    __shared__ float lpart[NSEG];

    wl[threadIdx.x] = (threadIdx.x < NC - 1) ? w[threadIdx.x] : 0.f;

    // ---- load this thread's 65-channel x slice into registers ----
    float xr[SEG + 1];
    #pragma unroll
    for (int j = 0; j < SEG; ++j)
        xr[j] = xp[(size_t)(k0 + j) * CST];
    float xtop = 0.f;
    if (s < NSEG - 1) xtop = xp[(size_t)(k0 + SEG) * CST];   // wave-uniform guard
    xr[SEG] = xtop;

    __syncthreads();   // wl visible

    // ---- phase A: per-segment partial sums (pure register math) ----
    float a = 0.f, bs = 0.f;
    #pragma unroll
    for (int j = 0; j < SEG; ++j) {
        const float wk = wl[k0 + j];          // broadcast read
        a  = fmaf(xr[j],     wk, a);          // A[k] = x[k]  * w[k]
        bs = fmaf(xr[j + 1], wk, bs);         // B[k] = x[k+1]* w[k]
    }
    sA[s][lane] = a;
    sB[s][lane] = bs;
    __syncthreads();

    // ---- g[k0] = sum_{t<s} A_t + sum_{t>=s} B_t ----
    float r = 0.f;
    #pragma unroll
    for (int t = 0; t < NSEG; ++t)
        r += (t < s) ? sA[t][lane] : sB[t][lane];

    // ---- phase B: emit g + loss (no loads — x is in registers) ----
    float ls = 0.f;
    #pragma unroll
    for (int j = 0; j < SEG; ++j) {
        gp[(size_t)(k0 + j) * CST] = r;
        const float d = r - xr[j];
        ls = fmaf(d, d, ls);
        r = fmaf(wl[k0 + j], xr[j] - xr[j + 1], r);   // g[k+1] = g[k] + w[k](x[k]-x[k+1])
    }

    // ---- loss: wave reduce -> block reduce -> one float per block ----
    #pragma unroll
    for (int off = 32; off; off >>= 1) ls += __shfl_down(ls, off, 64);
    if (lane == 0) lpart[s] = ls;
    __syncthreads();
    if (threadIdx.x == 0) {
        float t = 0.f;
        #pragma unroll
        for (int i = 0; i < NSEG; ++i) t += lpart[i];
        part[blockIdx.x] = t;
    }
}

__global__ __launch_bounds__(256) void k_final(const float* __restrict__ part,
                                               float* __restrict__ out) {
    double s = 0.0;
    for (int i = threadIdx.x; i < NBLK; i += 256) s += (double)part[i];
    #pragma unroll
    for (int off = 32; off; off >>= 1) s += __shfl_down(s, off, 64);
    __shared__ double sm[4];
    if ((threadIdx.x & 63) == 0) sm[threadIdx.x >> 6] = s;
    __syncthreads();
    if (threadIdx.x == 0)
        out[0] = (float)(sqrt(sm[0] + sm[1] + sm[2] + sm[3]) * 0.0025);
}

extern "C" void kernel_launch(void* const* d_in, const int* in_sizes, int n_in,
                              void* d_out, int out_size, void* d_ws, size_t ws_size,
                              hipStream_t stream) {
    const float* x = (const float*)d_in[0];
    const float* w = (const float*)d_in[1];
    float* g = (float*)d_out;
    float* part = (float*)d_ws;

    k_fused<<<dim3(NBLK), dim3(512), 0, stream>>>(x, w, g, part);
    k_final<<<1, 256, 0, stream>>>(part, g + GSZ);
}